// Round 2
// baseline (1163.762 us; speedup 1.0000x reference)
//
#include <hip/hip_runtime.h>

#define R_WS 8
#define F_NF 8
#define B_BATCH 4096
#define EMB_ROWS 200000
#define EMB_DIM 64
#define NBAGS (R_WS * F_NF * B_BATCH)   // 262144 = 2^18
#define RB_SZ (R_WS * B_BATCH)          // 32768  = 2^15
#define SCAN_NB 256                     // blocks in pass1/pass3
#define SCAN_BT 256                     // threads per scan block
#define SCAN_ITEMS 4                    // items/thread -> 1024/block

// Row-range blocking: process the embedding tables in NPASS sequential kernel
// launches, pass p touching only rows [p*ROWS_PER_PASS, (p+1)*ROWS_PER_PASS).
// Rationale (rocprof baseline): FETCH_SIZE showed each table byte fetched ~4.8x
// from HBM (1.96 GB vs 0.41 GB ideal) -> L3 not retaining the 51.2 MB active
// table. Halving the instantaneous row working set (25.6 MB) + halving the
// mean re-reference interval should let the Infinity Cache retain it. The
// launch boundary provides the global phase synchronization (stream-ordered,
// no cross-XCD coherence assumptions).
#define NPASS 2
#define ROWS_PER_PASS (EMB_ROWS / NPASS)  // 100000

typedef float vfloat4 __attribute__((ext_vector_type(4)));   // clang-native, works with nontemporal builtins

// output bag o = (f<<15) + (r<<12) + b  ->  input bag i = (r<<15) + (f<<12) + b
__device__ __forceinline__ int perm_src(int o) {
    int f  = o >> 15;
    int rb = o & (RB_SZ - 1);
    int r  = rb >> 12;
    int b2 = rb & (B_BATCH - 1);
    return (r << 15) + (f << 12) + b2;
}

// Pass 1: per-block sums of lengths in input order and permuted order.
__global__ __launch_bounds__(SCAN_BT) void scan_pass1(
        const int* __restrict__ lengths, int* __restrict__ bsums) {
    int b = blockIdx.x, t = threadIdx.x;
    int base = b * (SCAN_BT * SCAN_ITEMS) + t * SCAN_ITEMS;
    int s_in = 0, s_out = 0;
#pragma unroll
    for (int k = 0; k < SCAN_ITEMS; ++k) {
        s_in  += lengths[base + k];
        s_out += lengths[perm_src(base + k)];
    }
    __shared__ int lin[SCAN_BT], lout[SCAN_BT];
    lin[t] = s_in; lout[t] = s_out;
    __syncthreads();
    for (int d = SCAN_BT / 2; d > 0; d >>= 1) {
        if (t < d) { lin[t] += lin[t + d]; lout[t] += lout[t + d]; }
        __syncthreads();
    }
    if (t == 0) { bsums[b] = lin[0]; bsums[SCAN_NB + b] = lout[0]; }
}

// Pass 2: one block exclusive-scans both 256-element block-sum arrays in place.
__global__ __launch_bounds__(SCAN_BT) void scan_pass2(int* __restrict__ bsums) {
    int t = threadIdx.x;
    __shared__ int s[2 * SCAN_NB];
    int o1 = bsums[t], o2 = bsums[SCAN_NB + t];
    s[t] = o1; s[SCAN_NB + t] = o2;
    __syncthreads();
    for (int d = 1; d < SCAN_NB; d <<= 1) {
        int a = (t >= d) ? s[t - d] : 0;
        int c = (t >= d) ? s[SCAN_NB + t - d] : 0;
        __syncthreads();
        s[t] += a; s[SCAN_NB + t] += c;
        __syncthreads();
    }
    bsums[t] = s[t] - o1;                       // exclusive
    bsums[SCAN_NB + t] = s[SCAN_NB + t] - o2;
}

// Pass 3: rebuild local scans + block offset, write full off_in / off_out.
__global__ __launch_bounds__(SCAN_BT) void scan_pass3(
        const int* __restrict__ lengths, const int* __restrict__ bsums,
        int* __restrict__ off_in, int* __restrict__ off_out) {
    int b = blockIdx.x, t = threadIdx.x;
    int base = b * (SCAN_BT * SCAN_ITEMS) + t * SCAN_ITEMS;
    int vin[SCAN_ITEMS], vout[SCAN_ITEMS];
    int tin = 0, tout = 0;
#pragma unroll
    for (int k = 0; k < SCAN_ITEMS; ++k) {
        vin[k]  = lengths[base + k];
        vout[k] = lengths[perm_src(base + k)];
        tin += vin[k]; tout += vout[k];
    }
    __shared__ int sin_[SCAN_BT], sout_[SCAN_BT];
    sin_[t] = tin; sout_[t] = tout;
    __syncthreads();
    for (int d = 1; d < SCAN_BT; d <<= 1) {
        int a = (t >= d) ? sin_[t - d] : 0;
        int c = (t >= d) ? sout_[t - d] : 0;
        __syncthreads();
        sin_[t] += a; sout_[t] += c;
        __syncthreads();
    }
    int ebase_in  = sin_[t]  - tin  + bsums[b];
    int ebase_out = sout_[t] - tout + bsums[SCAN_NB + b];
    int run_i = 0, run_o = 0;
#pragma unroll
    for (int k = 0; k < SCAN_ITEMS; ++k) {
        off_in[base + k]  = ebase_in + run_i;  run_i += vin[k];
        off_out[base + k] = ebase_out + run_o; run_o += vout[k];
    }
}

// Main: one wave per output bag. Lane layout: g = lane>>4 picks one of 4 rows
// per step, s = lane&15 owns dims [4s..4s+3] as float4. One gather instruction
// moves 1 KB/wave (4 rows x 256 B); unroll 8 keeps ~8 KB/wave in flight.
// Pass p only accumulates rows in [lo, lo+ROWS_PER_PASS). Out-of-range slots
// are PREDICATED (safe-row load + weight-0 fma), not branched, so the 8-deep
// load pipeline stays intact (a branch would force vmcnt(0) per gather).
__global__ __launch_bounds__(256) void bag_kernel(
        const int* __restrict__ lengths, const int* __restrict__ indices,
        const float* __restrict__ emb,
        const int* __restrict__ off_in, const int* __restrict__ off_out,
        float* __restrict__ out_offsets, float* __restrict__ out_permuted,
        float* __restrict__ out_ly, int pass) {
    int wid  = (int)((blockIdx.x * blockDim.x + threadIdx.x) >> 6);
    int lane = threadIdx.x & 63;
    if (wid >= NBAGS) return;
    int o = wid;
    int f = o >> 15;
    int src = perm_src(o);
    int start = off_in[src];
    int len   = lengths[src];
    int obase = off_out[o];
    if (pass == 0 && lane == 0)
        out_offsets[o] = (float)(obase - off_out[f << 15]);  // per-feature restart
    const float* etab = emb + (size_t)f * ((size_t)EMB_ROWS * EMB_DIM);
    const int lo = pass * ROWS_PER_PASS;
    int g = lane >> 4;       // row-group 0..3
    int s = lane & 15;       // dim-group: owns dims 4s..4s+3
    float ax = 0.f, ay = 0.f, az = 0.f, aw = 0.f;
    for (int j0 = 0; j0 < len; j0 += 64) {
        int rem = len - j0;
        int n = rem < 64 ? rem : 64;
        int idx = 0;
        if (lane < n) {
            idx = __builtin_nontemporal_load(&indices[start + j0 + lane]); // coalesced, streaming
            if (pass == 0)
                __builtin_nontemporal_store((float)idx, &out_permuted[obase + j0 + lane]);
        }
        if (n == 64) {
#pragma unroll 8
            for (int jj = 0; jj < 16; ++jj) {
                int row = __shfl(idx, jj * 4 + g, 64);
                bool inr = (unsigned)(row - lo) < (unsigned)ROWS_PER_PASS;
                int rsel = inr ? row : lo;                    // safe in-range address
                const vfloat4* p = (const vfloat4*)(etab + (size_t)rsel * EMB_DIM + s * 4);
                vfloat4 v = *p;                               // 1 KB/wave gather (partial pass density)
                float w = inr ? 1.f : 0.f;
                ax = fmaf(v.x, w, ax); ay = fmaf(v.y, w, ay);
                az = fmaf(v.z, w, az); aw = fmaf(v.w, w, aw);
            }
        } else {
            int nj = (n + 3) >> 2;                            // wave-uniform
            for (int jj = 0; jj < nj; ++jj) {
                int k = jj * 4 + g;
                int row = __shfl(idx, k, 64);                 // k>=n reads idx=0, masked below
                bool ok = (k < n) && ((unsigned)(row - lo) < (unsigned)ROWS_PER_PASS);
                int rsel = ok ? row : lo;
                const vfloat4* p = (const vfloat4*)(etab + (size_t)rsel * EMB_DIM + s * 4);
                vfloat4 v = *p;
                float w = ok ? 1.f : 0.f;
                ax = fmaf(v.x, w, ax); ay = fmaf(v.y, w, ay);
                az = fmaf(v.z, w, az); aw = fmaf(v.w, w, aw);
            }
        }
    }
    // reduce the 4 row-groups (lanes s, s+16, s+32, s+48 hold partial dims 4s..4s+3)
    ax += __shfl_xor(ax, 16, 64); ay += __shfl_xor(ay, 16, 64);
    az += __shfl_xor(az, 16, 64); aw += __shfl_xor(aw, 16, 64);
    ax += __shfl_xor(ax, 32, 64); ay += __shfl_xor(ay, 32, 64);
    az += __shfl_xor(az, 32, 64); aw += __shfl_xor(aw, 32, 64);
    if (lane < 16) {                                          // 16 lanes x 16 B = 256 B store
        vfloat4 r; r.x = ax; r.y = ay; r.z = az; r.w = aw;
        vfloat4* dst = (vfloat4*)(out_ly + (size_t)o * EMB_DIM + s * 4);
        if (pass != 0) {                                      // stream-ordered RMW across passes
            vfloat4 old = __builtin_nontemporal_load(dst);
            r.x += old.x; r.y += old.y; r.z += old.z; r.w += old.w;
        }
        __builtin_nontemporal_store(r, dst);
    }
}

extern "C" void kernel_launch(void* const* d_in, const int* in_sizes, int n_in,
                              void* d_out, int out_size, void* d_ws, size_t ws_size,
                              hipStream_t stream) {
    const int*   lengths = (const int*)d_in[0];
    const int*   indices = (const int*)d_in[1];
    const float* emb     = (const float*)d_in[2];
    int T = in_sizes[1];

    int* off_in  = (int*)d_ws;            // NBAGS ints
    int* off_out = off_in + NBAGS;        // NBAGS ints
    int* bsums   = off_out + NBAGS;       // 2*SCAN_NB ints

    float* out          = (float*)d_out;
    float* out_offsets  = out;                    // F*RB  = 262144 (as fp32, exact)
    float* out_permuted = out + NBAGS;            // T     (as fp32, exact: <200000)
    float* out_ly       = out_permuted + T;       // F*RB*D = 16777216

    scan_pass1<<<SCAN_NB, SCAN_BT, 0, stream>>>(lengths, bsums);
    scan_pass2<<<1, SCAN_BT, 0, stream>>>(bsums);
    scan_pass3<<<SCAN_NB, SCAN_BT, 0, stream>>>(lengths, bsums, off_in, off_out);
    // 262144 waves, 4 waves/block -> 65536 blocks; NPASS row-range passes,
    // stream order guarantees pass p is visible before pass p+1's RMW.
    for (int p = 0; p < NPASS; ++p)
        bag_kernel<<<NBAGS / 4, 256, 0, stream>>>(lengths, indices, emb, off_in, off_out,
                                                  out_offsets, out_permuted, out_ly, p);
}

// Round 4
// 1032.127 us; speedup vs baseline: 1.1275x; 1.1275x over previous
//
#include <hip/hip_runtime.h>

#define R_WS 8
#define F_NF 8
#define B_BATCH 4096
#define EMB_ROWS 200000
#define EMB_DIM 64
#define NBAGS (R_WS * F_NF * B_BATCH)   // 262144 = 2^18
#define RB_SZ (R_WS * B_BATCH)          // 32768  = 2^15
#define SCAN_NB 256                     // blocks in pass1/pass3
#define SCAN_BT 256                     // threads per scan block
#define SCAN_ITEMS 4                    // items/thread -> 1024/block

// Round-2 post-mortem: row-range multi-pass FALSIFIED the L3-retention theory
// (total FETCH unchanged ~1.9 GB; miss ratio insensitive to window halving ->
// the operative cache is the per-XCD 4 MB L2, un-gameable for random rows).
// This version reverts to a single traversal and attacks the latency chain:
//  - 2 consecutive bags per wave: metadata (int2) + both chunk-0 index loads
//    issue up front; bag B's round-trips hide under bag A's gathers.
//  - next-chunk index prefetch: chunk j+1's idx load issues BEFORE chunk j's
//    gathers, so its latency hides under them (was: full drain + extra RT).

typedef float vfloat4 __attribute__((ext_vector_type(4)));   // clang-native, works with nontemporal builtins
typedef int   vint2   __attribute__((ext_vector_type(2)));

// output bag o = (f<<15) + (r<<12) + b  ->  input bag i = (r<<15) + (f<<12) + b
__device__ __forceinline__ int perm_src(int o) {
    int f  = o >> 15;
    int rb = o & (RB_SZ - 1);
    int r  = rb >> 12;
    int b2 = rb & (B_BATCH - 1);
    return (r << 15) + (f << 12) + b2;
}

// Pass 1: per-block sums of lengths in input order and permuted order.
__global__ __launch_bounds__(SCAN_BT) void scan_pass1(
        const int* __restrict__ lengths, int* __restrict__ bsums) {
    int b = blockIdx.x, t = threadIdx.x;
    int base = b * (SCAN_BT * SCAN_ITEMS) + t * SCAN_ITEMS;
    int s_in = 0, s_out = 0;
#pragma unroll
    for (int k = 0; k < SCAN_ITEMS; ++k) {
        s_in  += lengths[base + k];
        s_out += lengths[perm_src(base + k)];
    }
    __shared__ int lin[SCAN_BT], lout[SCAN_BT];
    lin[t] = s_in; lout[t] = s_out;
    __syncthreads();
    for (int d = SCAN_BT / 2; d > 0; d >>= 1) {
        if (t < d) { lin[t] += lin[t + d]; lout[t] += lout[t + d]; }
        __syncthreads();
    }
    if (t == 0) { bsums[b] = lin[0]; bsums[SCAN_NB + b] = lout[0]; }
}

// Pass 2: one block exclusive-scans both 256-element block-sum arrays in place.
__global__ __launch_bounds__(SCAN_BT) void scan_pass2(int* __restrict__ bsums) {
    int t = threadIdx.x;
    __shared__ int s[2 * SCAN_NB];
    int o1 = bsums[t], o2 = bsums[SCAN_NB + t];
    s[t] = o1; s[SCAN_NB + t] = o2;
    __syncthreads();
    for (int d = 1; d < SCAN_NB; d <<= 1) {
        int a = (t >= d) ? s[t - d] : 0;
        int c = (t >= d) ? s[SCAN_NB + t - d] : 0;
        __syncthreads();
        s[t] += a; s[SCAN_NB + t] += c;
        __syncthreads();
    }
    bsums[t] = s[t] - o1;                       // exclusive
    bsums[SCAN_NB + t] = s[SCAN_NB + t] - o2;
}

// Pass 3: rebuild local scans + block offset, write full off_in / off_out.
__global__ __launch_bounds__(SCAN_BT) void scan_pass3(
        const int* __restrict__ lengths, const int* __restrict__ bsums,
        int* __restrict__ off_in, int* __restrict__ off_out) {
    int b = blockIdx.x, t = threadIdx.x;
    int base = b * (SCAN_BT * SCAN_ITEMS) + t * SCAN_ITEMS;
    int vin[SCAN_ITEMS], vout[SCAN_ITEMS];
    int tin = 0, tout = 0;
#pragma unroll
    for (int k = 0; k < SCAN_ITEMS; ++k) {
        vin[k]  = lengths[base + k];
        vout[k] = lengths[perm_src(base + k)];
        tin += vin[k]; tout += vout[k];
    }
    __shared__ int sin_[SCAN_BT], sout_[SCAN_BT];
    sin_[t] = tin; sout_[t] = tout;
    __syncthreads();
    for (int d = 1; d < SCAN_BT; d <<= 1) {
        int a = (t >= d) ? sin_[t - d] : 0;
        int c = (t >= d) ? sout_[t - d] : 0;
        __syncthreads();
        sin_[t] += a; sout_[t] += c;
        __syncthreads();
    }
    int ebase_in  = sin_[t]  - tin  + bsums[b];
    int ebase_out = sout_[t] - tout + bsums[SCAN_NB + b];
    int run_i = 0, run_o = 0;
#pragma unroll
    for (int k = 0; k < SCAN_ITEMS; ++k) {
        off_in[base + k]  = ebase_in + run_i;  run_i += vin[k];
        off_out[base + k] = ebase_out + run_o; run_o += vout[k];
    }
}

// Accumulate one bag. idx0 = preloaded chunk-0 indices (lane-resident).
// Lane layout: g = lane>>4 picks one of 4 rows/step, s = lane&15 owns dims
// [4s..4s+3]. One gather instr moves 1 KB/wave (4 rows x 256 B); unroll 8
// keeps ~8 KB/wave in flight. Chunk j+1's idx load is issued BEFORE chunk j's
// gathers: vmcnt order makes its wait cost ~0 (it's the oldest outstanding).
__device__ __forceinline__ void bag_accum(
        int o, int start, int len, int obase, int idx0,
        const int* __restrict__ indices, const float* __restrict__ etab,
        float* __restrict__ out_permuted, float* __restrict__ out_ly,
        int lane, int g, int s) {
    float ax = 0.f, ay = 0.f, az = 0.f, aw = 0.f;
    int idx = idx0;
    for (int j0 = 0; j0 < len; j0 += 64) {
        int rem = len - j0;
        int n = rem < 64 ? rem : 64;
        if (lane < n)
            __builtin_nontemporal_store((float)idx, &out_permuted[obase + j0 + lane]);
        int idx_next = 0;
        int j1 = j0 + 64;
        if (j1 < len) {                                        // prefetch next chunk
            int rem2 = len - j1;
            int n2 = rem2 < 64 ? rem2 : 64;
            if (lane < n2)
                idx_next = __builtin_nontemporal_load(&indices[start + j1 + lane]);
        }
        if (n == 64) {
#pragma unroll 8
            for (int jj = 0; jj < 16; ++jj) {
                int row = __shfl(idx, jj * 4 + g, 64);
                const vfloat4* p = (const vfloat4*)(etab + (size_t)row * EMB_DIM + s * 4);
                vfloat4 v = *p;                                // 1 KB/wave gather
                ax += v.x; ay += v.y; az += v.z; aw += v.w;
            }
        } else {
            int nj = (n + 3) >> 2;                             // wave-uniform
            for (int jj = 0; jj < nj; ++jj) {
                int k = jj * 4 + g;
                int row = __shfl(idx, k, 64);                  // k>=n reads idx=0, masked below
                if (k < n) {
                    const vfloat4* p = (const vfloat4*)(etab + (size_t)row * EMB_DIM + s * 4);
                    vfloat4 v = *p;
                    ax += v.x; ay += v.y; az += v.z; aw += v.w;
                }
            }
        }
        idx = idx_next;
    }
    // reduce the 4 row-groups (lanes s, s+16, s+32, s+48 hold partial dims 4s..4s+3)
    ax += __shfl_xor(ax, 16, 64); ay += __shfl_xor(ay, 16, 64);
    az += __shfl_xor(az, 16, 64); aw += __shfl_xor(aw, 16, 64);
    ax += __shfl_xor(ax, 32, 64); ay += __shfl_xor(ay, 32, 64);
    az += __shfl_xor(az, 32, 64); aw += __shfl_xor(aw, 32, 64);
    if (lane < 16) {                                           // 16 lanes x 16 B = 256 B store
        vfloat4 r; r.x = ax; r.y = ay; r.z = az; r.w = aw;
        __builtin_nontemporal_store(r, (vfloat4*)(out_ly + (size_t)o * EMB_DIM + s * 4));
    }
}

// Main: one wave per PAIR of consecutive output bags (same feature; adjacent
// metadata -> int2 loads share cache lines). Both bags' metadata + chunk-0
// index loads are issued up front so bag B's round-trips hide under bag A.
__global__ __launch_bounds__(256, 8) void bag_kernel(
        const int* __restrict__ lengths, const int* __restrict__ indices,
        const float* __restrict__ emb,
        const int* __restrict__ off_in, const int* __restrict__ off_out,
        float* __restrict__ out_offsets, float* __restrict__ out_permuted,
        float* __restrict__ out_ly) {
    int wp   = (int)((blockIdx.x * blockDim.x + threadIdx.x) >> 6);
    int lane = threadIdx.x & 63;
    if (wp >= NBAGS / 2) return;
    int oA = wp << 1;                    // even; oA+1 same feature (f boundary is 2^15)
    int f  = oA >> 15;
    int srcA = perm_src(oA);             // even; perm_src(oA+1) == srcA+1 (b2 even < 4095)
    vint2 st = *(const vint2*)&off_in[srcA];
    vint2 ln = *(const vint2*)&lengths[srcA];
    vint2 ob = *(const vint2*)&off_out[oA];
    int basef = off_out[f << 15];
    int g = lane >> 4;                   // row-group 0..3
    int s = lane & 15;                   // dim-group: owns dims 4s..4s+3
    // chunk-0 index prefetch for BOTH bags: the two RTs overlap, and bag B's
    // value stays lane-resident until its compute phase.
    int nA0 = ln.x < 64 ? ln.x : 64;
    int nB0 = ln.y < 64 ? ln.y : 64;
    int idxA0 = 0, idxB0 = 0;
    if (lane < nA0) idxA0 = __builtin_nontemporal_load(&indices[st.x + lane]);
    if (lane < nB0) idxB0 = __builtin_nontemporal_load(&indices[st.y + lane]);
    if (lane == 0) {                     // per-feature restart offsets
        out_offsets[oA]     = (float)(ob.x - basef);
        out_offsets[oA + 1] = (float)(ob.y - basef);
    }
    const float* etab = emb + (size_t)f * ((size_t)EMB_ROWS * EMB_DIM);
    bag_accum(oA,     st.x, ln.x, ob.x, idxA0, indices, etab, out_permuted, out_ly, lane, g, s);
    bag_accum(oA + 1, st.y, ln.y, ob.y, idxB0, indices, etab, out_permuted, out_ly, lane, g, s);
}

extern "C" void kernel_launch(void* const* d_in, const int* in_sizes, int n_in,
                              void* d_out, int out_size, void* d_ws, size_t ws_size,
                              hipStream_t stream) {
    const int*   lengths = (const int*)d_in[0];
    const int*   indices = (const int*)d_in[1];
    const float* emb     = (const float*)d_in[2];
    int T = in_sizes[1];

    int* off_in  = (int*)d_ws;            // NBAGS ints
    int* off_out = off_in + NBAGS;        // NBAGS ints
    int* bsums   = off_out + NBAGS;       // 2*SCAN_NB ints

    float* out          = (float*)d_out;
    float* out_offsets  = out;                    // F*RB  = 262144 (as fp32, exact)
    float* out_permuted = out + NBAGS;            // T     (as fp32, exact: <200000)
    float* out_ly       = out_permuted + T;       // F*RB*D = 16777216

    scan_pass1<<<SCAN_NB, SCAN_BT, 0, stream>>>(lengths, bsums);
    scan_pass2<<<1, SCAN_BT, 0, stream>>>(bsums);
    scan_pass3<<<SCAN_NB, SCAN_BT, 0, stream>>>(lengths, bsums, off_in, off_out);
    // 131072 bag-pair waves, 4 waves/block -> 32768 blocks
    bag_kernel<<<NBAGS / 8, 256, 0, stream>>>(lengths, indices, emb, off_in, off_out,
                                              out_offsets, out_permuted, out_ly);
}